// Round 1
// baseline (5385.992 us; speedup 1.0000x reference)
//
#include <hip/hip_runtime.h>

#define EPS 1e-5f

// ---------------- conv1: 5x5, 3->32, pad2 + BN + ReLU + maxpool2 ----------------
// x[512,3,64,64] -> h1[512,32,32,32].  One block per (n, c); thread = pooled pixel(s).
__global__ __launch_bounds__(256) void k_conv1(
    const float* __restrict__ x, const float* __restrict__ w,
    const float* __restrict__ bg, const float* __restrict__ bb,
    const float* __restrict__ bm, const float* __restrict__ bv,
    float* __restrict__ out)
{
    __shared__ float wl[75];
    const int blk = blockIdx.x;
    const int n = blk >> 5;
    const int c = blk & 31;
    const int t = threadIdx.x;
    if (t < 75) wl[t] = w[c * 75 + t];
    __syncthreads();
    const float sc = bg[c] * rsqrtf(bv[c] + EPS);
    const float bs = bb[c] - bm[c] * sc;
    const float* xp = x + (size_t)n * 3 * 4096;
    float* op = out + ((size_t)n * 32 + c) * 1024;
    for (int p = t; p < 1024; p += 256) {
        const int py = p >> 5, px = p & 31;
        float a00 = 0.f, a01 = 0.f, a10 = 0.f, a11 = 0.f;
        for (int ci = 0; ci < 3; ++ci) {
            const float* ip = xp + ci * 4096;
            float patch[6][6];
            #pragma unroll
            for (int i = 0; i < 6; ++i) {
                const int r = 2 * py - 2 + i;
                const bool rv = ((unsigned)r < 64u);
                #pragma unroll
                for (int j = 0; j < 6; ++j) {
                    const int cc = 2 * px - 2 + j;
                    patch[i][j] = (rv && (unsigned)cc < 64u) ? __ldg(ip + r * 64 + cc) : 0.f;
                }
            }
            const float* wp = wl + ci * 25;
            #pragma unroll
            for (int ky = 0; ky < 5; ++ky) {
                #pragma unroll
                for (int kx = 0; kx < 5; ++kx) {
                    const float wv = wp[ky * 5 + kx];
                    a00 = fmaf(patch[ky    ][kx    ], wv, a00);
                    a01 = fmaf(patch[ky    ][kx + 1], wv, a01);
                    a10 = fmaf(patch[ky + 1][kx    ], wv, a10);
                    a11 = fmaf(patch[ky + 1][kx + 1], wv, a11);
                }
            }
        }
        a00 = fmaxf(fmaf(a00, sc, bs), 0.f);
        a01 = fmaxf(fmaf(a01, sc, bs), 0.f);
        a10 = fmaxf(fmaf(a10, sc, bs), 0.f);
        a11 = fmaxf(fmaf(a11, sc, bs), 0.f);
        op[p] = fmaxf(fmaxf(a00, a01), fmaxf(a10, a11));
    }
}

// ---------------- conv2: 3x3, 32->64, pad1 + BN + ReLU + maxpool2 ----------------
// h1[512,32,32,32] -> h2[512,64,16,16].  Block per (n, co); thread = one pooled pixel.
__global__ __launch_bounds__(256) void k_conv2(
    const float* __restrict__ x, const float* __restrict__ w,
    const float* __restrict__ bg, const float* __restrict__ bb,
    const float* __restrict__ bm, const float* __restrict__ bv,
    float* __restrict__ out)
{
    __shared__ float wl[288];
    const int blk = blockIdx.x;
    const int n = blk >> 6;
    const int co = blk & 63;
    const int t = threadIdx.x;
    for (int i = t; i < 288; i += 256) wl[i] = w[co * 288 + i];
    __syncthreads();
    const float sc = bg[co] * rsqrtf(bv[co] + EPS);
    const float bs = bb[co] - bm[co] * sc;
    const float* xp = x + (size_t)n * 32 * 1024;
    const int py = t >> 4, px = t & 15;
    float a00 = 0.f, a01 = 0.f, a10 = 0.f, a11 = 0.f;
    for (int ci = 0; ci < 32; ++ci) {
        const float* ip = xp + ci * 1024;
        float patch[4][4];
        #pragma unroll
        for (int i = 0; i < 4; ++i) {
            const int r = 2 * py - 1 + i;
            const bool rv = ((unsigned)r < 32u);
            #pragma unroll
            for (int j = 0; j < 4; ++j) {
                const int cc = 2 * px - 1 + j;
                patch[i][j] = (rv && (unsigned)cc < 32u) ? __ldg(ip + r * 32 + cc) : 0.f;
            }
        }
        const float* wp = wl + ci * 9;
        #pragma unroll
        for (int ky = 0; ky < 3; ++ky) {
            #pragma unroll
            for (int kx = 0; kx < 3; ++kx) {
                const float wv = wp[ky * 3 + kx];
                a00 = fmaf(patch[ky    ][kx    ], wv, a00);
                a01 = fmaf(patch[ky    ][kx + 1], wv, a01);
                a10 = fmaf(patch[ky + 1][kx    ], wv, a10);
                a11 = fmaf(patch[ky + 1][kx + 1], wv, a11);
            }
        }
    }
    a00 = fmaxf(fmaf(a00, sc, bs), 0.f);
    a01 = fmaxf(fmaf(a01, sc, bs), 0.f);
    a10 = fmaxf(fmaf(a10, sc, bs), 0.f);
    a11 = fmaxf(fmaf(a11, sc, bs), 0.f);
    out[(((size_t)n * 64 + co) * 16 + py) * 16 + px] = fmaxf(fmaxf(a00, a01), fmaxf(a10, a11));
}

// ---------------- conv3: 3x3, 64->128, pad1 + BN + ReLU + maxpool2 ----------------
// h2[512,64,16,16] -> h3[512,128,8,8].  Block per (ngrp of 4 images, co); thread = (n_sub, pooled pixel).
__global__ __launch_bounds__(256) void k_conv3(
    const float* __restrict__ x, const float* __restrict__ w,
    const float* __restrict__ bg, const float* __restrict__ bb,
    const float* __restrict__ bm, const float* __restrict__ bv,
    float* __restrict__ out)
{
    __shared__ float wl[576];
    const int blk = blockIdx.x;
    const int ngrp = blk >> 7;
    const int co = blk & 127;
    const int t = threadIdx.x;
    for (int i = t; i < 576; i += 256) wl[i] = w[co * 576 + i];
    __syncthreads();
    const float sc = bg[co] * rsqrtf(bv[co] + EPS);
    const float bs = bb[co] - bm[co] * sc;
    const int n = ngrp * 4 + (t >> 6);
    const int p = t & 63;
    const int py = p >> 3, px = p & 7;
    const float* xp = x + (size_t)n * 64 * 256;
    float a00 = 0.f, a01 = 0.f, a10 = 0.f, a11 = 0.f;
    for (int ci = 0; ci < 64; ++ci) {
        const float* ip = xp + ci * 256;
        float patch[4][4];
        #pragma unroll
        for (int i = 0; i < 4; ++i) {
            const int r = 2 * py - 1 + i;
            const bool rv = ((unsigned)r < 16u);
            #pragma unroll
            for (int j = 0; j < 4; ++j) {
                const int cc = 2 * px - 1 + j;
                patch[i][j] = (rv && (unsigned)cc < 16u) ? __ldg(ip + r * 16 + cc) : 0.f;
            }
        }
        const float* wp = wl + ci * 9;
        #pragma unroll
        for (int ky = 0; ky < 3; ++ky) {
            #pragma unroll
            for (int kx = 0; kx < 3; ++kx) {
                const float wv = wp[ky * 3 + kx];
                a00 = fmaf(patch[ky    ][kx    ], wv, a00);
                a01 = fmaf(patch[ky    ][kx + 1], wv, a01);
                a10 = fmaf(patch[ky + 1][kx    ], wv, a10);
                a11 = fmaf(patch[ky + 1][kx + 1], wv, a11);
            }
        }
    }
    a00 = fmaxf(fmaf(a00, sc, bs), 0.f);
    a01 = fmaxf(fmaf(a01, sc, bs), 0.f);
    a10 = fmaxf(fmaf(a10, sc, bs), 0.f);
    a11 = fmaxf(fmaf(a11, sc, bs), 0.f);
    out[(((size_t)n * 128 + co) * 8 + py) * 8 + px] = fmaxf(fmaxf(a00, a01), fmaxf(a10, a11));
}

// ---------------- FC: [512,8192] @ [256,8192]^T, split-K=8, atomic accumulate ----------------
__global__ __launch_bounds__(256) void k_fc(
    const float* __restrict__ A, const float* __restrict__ Bw, float* __restrict__ C)
{
    __shared__ float As[64][33];
    __shared__ float Bs[64][33];
    const int bm = blockIdx.x, bn = blockIdx.y, kz = blockIdx.z;
    const int t = threadIdx.x;
    const int tm = t >> 4, tn = t & 15;
    float acc[4][4] = {};
    const int k0 = kz * 1024;
    for (int kt = 0; kt < 1024; kt += 32) {
        #pragma unroll
        for (int u = 0; u < 2; ++u) {
            const int f = t + u * 256;
            const int row = f >> 3;
            const int col = (f & 7) * 4;
            const float4 av = *reinterpret_cast<const float4*>(
                &A[(size_t)(bm * 64 + row) * 8192 + k0 + kt + col]);
            As[row][col] = av.x; As[row][col + 1] = av.y;
            As[row][col + 2] = av.z; As[row][col + 3] = av.w;
            const float4 bvv = *reinterpret_cast<const float4*>(
                &Bw[(size_t)(bn * 64 + row) * 8192 + k0 + kt + col]);
            Bs[row][col] = bvv.x; Bs[row][col + 1] = bvv.y;
            Bs[row][col + 2] = bvv.z; Bs[row][col + 3] = bvv.w;
        }
        __syncthreads();
        #pragma unroll
        for (int kk = 0; kk < 32; ++kk) {
            float av[4], bv2[4];
            #pragma unroll
            for (int i = 0; i < 4; ++i) av[i] = As[tm * 4 + i][kk];
            #pragma unroll
            for (int i = 0; i < 4; ++i) bv2[i] = Bs[tn * 4 + i][kk];
            #pragma unroll
            for (int i = 0; i < 4; ++i)
                #pragma unroll
                for (int j = 0; j < 4; ++j)
                    acc[i][j] = fmaf(av[i], bv2[j], acc[i][j]);
        }
        __syncthreads();
    }
    #pragma unroll
    for (int i = 0; i < 4; ++i)
        #pragma unroll
        for (int j = 0; j < 4; ++j)
            atomicAdd(&C[(size_t)(bm * 64 + tm * 4 + i) * 256 + bn * 64 + tn * 4 + j], acc[i][j]);
}

// ---------------- heads: BN+ReLU(s) -> two 256->64 FCs + BN + ReLU -> 64->1 dots ----------------
__global__ __launch_bounds__(128) void k_heads(
    const float* __restrict__ sraw, const float* __restrict__ fcb,
    const float* __restrict__ fg, const float* __restrict__ fb,
    const float* __restrict__ fm, const float* __restrict__ fv,
    const float* __restrict__ cw1, const float* __restrict__ cb1,
    const float* __restrict__ cg, const float* __restrict__ cbb,
    const float* __restrict__ cm, const float* __restrict__ cv,
    const float* __restrict__ cw2, const float* __restrict__ cb2,
    const float* __restrict__ mw1, const float* __restrict__ mb1,
    const float* __restrict__ mg, const float* __restrict__ mbb,
    const float* __restrict__ mm, const float* __restrict__ mv,
    const float* __restrict__ mw2, const float* __restrict__ mb2,
    float* __restrict__ outp)
{
    __shared__ float sv[256];
    const int b = blockIdx.x, t = threadIdx.x;
    for (int k = t; k < 256; k += 128) {
        const float val = sraw[b * 256 + k] + fcb[k];
        const float s = fg[k] * rsqrtf(fv[k] + EPS);
        sv[k] = fmaxf(fmaf(val, s, fb[k] - fm[k] * s), 0.f);
    }
    __syncthreads();
    const int j = t & 63;
    const bool isM = (t >= 64);
    const float* w1  = isM ? mw1 : cw1;
    const float* b1  = isM ? mb1 : cb1;
    const float* g1  = isM ? mg  : cg;
    const float* bb1 = isM ? mbb : cbb;
    const float* m1  = isM ? mm  : cm;
    const float* v1  = isM ? mv  : cv;
    const float* w2  = isM ? mw2 : cw2;
    const float* b2  = isM ? mb2 : cb2;
    float d = 0.f;
    const float* wr = w1 + j * 256;
    #pragma unroll 8
    for (int k = 0; k < 256; ++k) d = fmaf(sv[k], wr[k], d);
    d += b1[j];
    const float s1 = g1[j] * rsqrtf(v1[j] + EPS);
    d = fmaxf(fmaf(d, s1, bb1[j] - m1[j] * s1), 0.f);
    float prod = d * w2[j];
    #pragma unroll
    for (int off = 32; off > 0; off >>= 1) prod += __shfl_down(prod, off);
    if (j == 0) outp[(isM ? 512 : 0) + b] = prod + b2[0];
}

extern "C" void kernel_launch(void* const* d_in, const int* in_sizes, int n_in,
                              void* d_out, int out_size, void* d_ws, size_t ws_size,
                              hipStream_t stream)
{
    const float* x    = (const float*)d_in[0];
    const float* w1   = (const float*)d_in[1];
    const float* bn1g = (const float*)d_in[2];
    const float* bn1b = (const float*)d_in[3];
    const float* bn1m = (const float*)d_in[4];
    const float* bn1v = (const float*)d_in[5];
    const float* w2   = (const float*)d_in[6];
    const float* bn2g = (const float*)d_in[7];
    const float* bn2b = (const float*)d_in[8];
    const float* bn2m = (const float*)d_in[9];
    const float* bn2v = (const float*)d_in[10];
    const float* w3   = (const float*)d_in[11];
    const float* bn3g = (const float*)d_in[12];
    const float* bn3b = (const float*)d_in[13];
    const float* bn3m = (const float*)d_in[14];
    const float* bn3v = (const float*)d_in[15];
    const float* fcw  = (const float*)d_in[16];
    const float* fcb  = (const float*)d_in[17];
    const float* bnfg = (const float*)d_in[18];
    const float* bnfb = (const float*)d_in[19];
    const float* bnfm = (const float*)d_in[20];
    const float* bnfv = (const float*)d_in[21];
    const float* cw1  = (const float*)d_in[22];
    const float* cb1  = (const float*)d_in[23];
    const float* bncg = (const float*)d_in[24];
    const float* bncb = (const float*)d_in[25];
    const float* bncm = (const float*)d_in[26];
    const float* bncv = (const float*)d_in[27];
    const float* cw2  = (const float*)d_in[28];
    const float* cb2  = (const float*)d_in[29];
    const float* mw1  = (const float*)d_in[30];
    const float* mb1  = (const float*)d_in[31];
    const float* bnmg = (const float*)d_in[32];
    const float* bnmb = (const float*)d_in[33];
    const float* bnmm = (const float*)d_in[34];
    const float* bnmv = (const float*)d_in[35];
    const float* mw2  = (const float*)d_in[36];
    const float* mb2  = (const float*)d_in[37];

    float* ws = (float*)d_ws;
    float* h1 = ws;                                  // 512*32*32*32 = 16,777,216 f (64 MB)
    float* h2 = h1 + (size_t)512 * 32 * 32 * 32;     // 512*64*16*16 =  8,388,608 f (32 MB)
    float* h3 = h2 + (size_t)512 * 64 * 16 * 16;     // 512*128*8*8  =  4,194,304 f (16 MB)
    float* sr = h3 + (size_t)512 * 128 * 8 * 8;      // 512*256      =    131,072 f (0.5 MB)
    float* outp = (float*)d_out;

    k_conv1<<<512 * 32, 256, 0, stream>>>(x, w1, bn1g, bn1b, bn1m, bn1v, h1);
    k_conv2<<<512 * 64, 256, 0, stream>>>(h1, w2, bn2g, bn2b, bn2m, bn2v, h2);
    k_conv3<<<128 * 128, 256, 0, stream>>>(h2, w3, bn3g, bn3b, bn3m, bn3v, h3);
    hipMemsetAsync(sr, 0, (size_t)512 * 256 * sizeof(float), stream);
    k_fc<<<dim3(8, 4, 8), 256, 0, stream>>>(h3, fcw, sr);
    k_heads<<<512, 128, 0, stream>>>(sr, fcb, bnfg, bnfb, bnfm, bnfv,
                                     cw1, cb1, bncg, bncb, bncm, bncv, cw2, cb2,
                                     mw1, mb1, bnmg, bnmb, bnmm, bnmv, mw2, mb2, outp);
}

// Round 2
// 837.036 us; speedup vs baseline: 6.4346x; 6.4346x over previous
//
#include <hip/hip_runtime.h>

#define EPS 1e-5f

// ---------------- conv1: 5x5, 3->32, pad2 + BN + ReLU + maxpool2 ----------------
// x[512,3,64,64] -> h1[512,32,32,32]. Block = (n, 4-pooled-row strip q of 8).
// Thread: cg=t>>5 (4 co), slot=t&31: sr=slot>>3 (pooled row), scol=slot&7 (4 pooled cols).
__global__ __launch_bounds__(256) void k_conv1(
    const float* __restrict__ x, const float* __restrict__ w,
    const float* __restrict__ bg, const float* __restrict__ bb,
    const float* __restrict__ bm, const float* __restrict__ bv,
    float* __restrict__ out)
{
    __shared__ float xs[3 * 12 * 70];   // rows 8q-2..8q+9, cols shifted +2, stride 70
    __shared__ float ws[3 * 25 * 32];   // [ci][k][co]
    const int blk = blockIdx.x;
    const int n = blk >> 3, q = blk & 7;
    const int t = threadIdx.x;

    for (int idx = t; idx < 2520; idx += 256) {
        const int ci = idx / 840; const int rem = idx - ci * 840;
        const int row = rem / 70; const int col = rem - row * 70;
        const int gr = 8 * q - 2 + row, gc = col - 2;
        float v = 0.f;
        if ((unsigned)gr < 64u && (unsigned)gc < 64u)
            v = x[((size_t)(n * 3 + ci) << 12) + (gr << 6) + gc];
        xs[idx] = v;
    }
    for (int idx = t; idx < 2400; idx += 256) {
        const int ci = idx / 800; const int rem = idx - ci * 800;
        const int k = rem >> 5; const int co = rem & 31;
        ws[idx] = w[(co * 3 + ci) * 25 + k];
    }
    __syncthreads();

    const int cg = t >> 5, slot = t & 31;
    const int sr = slot >> 3, scol = slot & 7;

    float acc[4][16];
    #pragma unroll
    for (int i = 0; i < 4; ++i)
        #pragma unroll
        for (int j = 0; j < 16; ++j) acc[i][j] = 0.f;

    for (int ci = 0; ci < 3; ++ci) {
        const float* xci = xs + ci * 840;
        const float* wci = ws + ci * 800 + 4 * cg;
        #pragma unroll
        for (int ky = 0; ky < 5; ++ky) {
            float wv[5][4];
            #pragma unroll
            for (int kx = 0; kx < 5; ++kx)
                *reinterpret_cast<float4*>(wv[kx]) =
                    *reinterpret_cast<const float4*>(&wci[(ky * 5 + kx) * 32]);
            #pragma unroll
            for (int rr = 0; rr < 2; ++rr) {
                const float* rp = xci + (2 * sr + rr + ky) * 70 + 8 * scol;
                float row[12];
                #pragma unroll
                for (int e = 0; e < 6; ++e)
                    *reinterpret_cast<float2*>(&row[2 * e]) =
                        *reinterpret_cast<const float2*>(&rp[2 * e]);
                #pragma unroll
                for (int cc = 0; cc < 8; ++cc)
                    #pragma unroll
                    for (int kx = 0; kx < 5; ++kx)
                        #pragma unroll
                        for (int co = 0; co < 4; ++co)
                            acc[co][rr * 8 + cc] = fmaf(row[cc + kx], wv[kx][co], acc[co][rr * 8 + cc]);
            }
        }
    }

    const int pr = 4 * q + sr;
    #pragma unroll
    for (int co_l = 0; co_l < 4; ++co_l) {
        const int co = 4 * cg + co_l;
        const float s = bg[co] * rsqrtf(bv[co] + EPS);
        const float bsv = bb[co] - bm[co] * s;
        #pragma unroll
        for (int pcc = 0; pcc < 4; ++pcc) {
            const float v0 = fmaxf(fmaf(acc[co_l][2 * pcc],     s, bsv), 0.f);
            const float v1 = fmaxf(fmaf(acc[co_l][2 * pcc + 1], s, bsv), 0.f);
            const float v2 = fmaxf(fmaf(acc[co_l][8 + 2 * pcc],     s, bsv), 0.f);
            const float v3 = fmaxf(fmaf(acc[co_l][8 + 2 * pcc + 1], s, bsv), 0.f);
            out[(((size_t)n * 32 + co) * 32 + pr) * 32 + 4 * scol + pcc] =
                fmaxf(fmaxf(v0, v1), fmaxf(v2, v3));
        }
    }
}

// ---------------- conv2: 3x3, 32->64, pad1 + BN + ReLU + maxpool2 ----------------
// h1[512,32,32,32] -> h2[512,64,16,16]. Block = (n, 4-pooled-row strip q of 4).
// Thread: cg=t>>4 (4 co), slot=t&15: sr=slot>>2 (pooled row), scol=slot&3 (4 pooled cols).
__global__ __launch_bounds__(256) void k_conv2(
    const float* __restrict__ x, const float* __restrict__ w,
    const float* __restrict__ bg, const float* __restrict__ bb,
    const float* __restrict__ bm, const float* __restrict__ bv,
    float* __restrict__ out)
{
    __shared__ float xs[8 * 380];   // 8 ci * [10 rows][stride 38], cols shifted +1
    __shared__ float ws[8 * 576];   // [ci][9][64]
    const int blk = blockIdx.x;
    const int n = blk >> 2, q = blk & 3;
    const int t = threadIdx.x;
    const int cg = t >> 4, slot = t & 15;
    const int sr = slot >> 2, scol = slot & 3;

    float acc[4][16];
    #pragma unroll
    for (int i = 0; i < 4; ++i)
        #pragma unroll
        for (int j = 0; j < 16; ++j) acc[i][j] = 0.f;

    for (int g = 0; g < 4; ++g) {
        const int ci0 = g * 8;
        __syncthreads();
        for (int idx = t; idx < 3040; idx += 256) {
            const int ci = idx / 380; const int rem = idx - ci * 380;
            const int row = rem / 38; const int col = rem - row * 38;
            const int gr = 8 * q - 1 + row, gc = col - 1;
            float v = 0.f;
            if ((unsigned)gr < 32u && (unsigned)gc < 32u)
                v = x[(((size_t)n * 32 + ci0 + ci) << 10) + (gr << 5) + gc];
            xs[idx] = v;
        }
        for (int idx = t; idx < 4608; idx += 256) {
            const int l = idx / 576; const int rem = idx - l * 576;
            const int co = rem / 9; const int k = rem - co * 9;
            ws[l * 576 + k * 64 + co] = w[(co * 32 + ci0 + l) * 9 + k];
        }
        __syncthreads();
        for (int l = 0; l < 8; ++l) {
            const float* xci = xs + l * 380;
            const float* wci = ws + l * 576 + 4 * cg;
            #pragma unroll
            for (int ky = 0; ky < 3; ++ky) {
                float wv[3][4];
                #pragma unroll
                for (int kx = 0; kx < 3; ++kx)
                    *reinterpret_cast<float4*>(wv[kx]) =
                        *reinterpret_cast<const float4*>(&wci[(ky * 3 + kx) * 64]);
                #pragma unroll
                for (int rr = 0; rr < 2; ++rr) {
                    const float* rp = xci + (2 * sr + rr + ky) * 38 + 8 * scol;
                    float row[12];
                    #pragma unroll
                    for (int e = 0; e < 6; ++e)
                        *reinterpret_cast<float2*>(&row[2 * e]) =
                            *reinterpret_cast<const float2*>(&rp[2 * e]);
                    #pragma unroll
                    for (int cc = 0; cc < 8; ++cc)
                        #pragma unroll
                        for (int kx = 0; kx < 3; ++kx)
                            #pragma unroll
                            for (int co = 0; co < 4; ++co)
                                acc[co][rr * 8 + cc] = fmaf(row[cc + kx], wv[kx][co], acc[co][rr * 8 + cc]);
                }
            }
        }
    }

    const int pr = 4 * q + sr;
    #pragma unroll
    for (int co_l = 0; co_l < 4; ++co_l) {
        const int co = 4 * cg + co_l;
        const float s = bg[co] * rsqrtf(bv[co] + EPS);
        const float bsv = bb[co] - bm[co] * s;
        #pragma unroll
        for (int pcc = 0; pcc < 4; ++pcc) {
            const float v0 = fmaxf(fmaf(acc[co_l][2 * pcc],     s, bsv), 0.f);
            const float v1 = fmaxf(fmaf(acc[co_l][2 * pcc + 1], s, bsv), 0.f);
            const float v2 = fmaxf(fmaf(acc[co_l][8 + 2 * pcc],     s, bsv), 0.f);
            const float v3 = fmaxf(fmaf(acc[co_l][8 + 2 * pcc + 1], s, bsv), 0.f);
            out[(((size_t)n * 64 + co) * 16 + pr) * 16 + 4 * scol + pcc] =
                fmaxf(fmaxf(v0, v1), fmaxf(v2, v3));
        }
    }
}

// ---------------- conv3: 3x3, 64->128, pad1 + BN + ReLU + maxpool2 ----------------
// h2[512,64,16,16] -> h3[512,128,8,8]. Block = (n, co-half ch of 2).
// Thread: cg=t>>4 (4 co of the half), slot=t&15: sr=slot>>1 (pooled row 0..7), sh=slot&1 (4 pooled cols).
__global__ __launch_bounds__(256) void k_conv3(
    const float* __restrict__ x, const float* __restrict__ w,
    const float* __restrict__ bg, const float* __restrict__ bb,
    const float* __restrict__ bm, const float* __restrict__ bv,
    float* __restrict__ out)
{
    __shared__ float xs[8 * 396];   // 8 ci * [18 rows][stride 22], shifted +1
    __shared__ float ws[8 * 576];   // [ci][9][64]
    const int blk = blockIdx.x;
    const int n = blk >> 1, ch = blk & 1;
    const int t = threadIdx.x;
    const int cg = t >> 4, slot = t & 15;
    const int sr = slot >> 1, sh = slot & 1;

    float acc[4][16];
    #pragma unroll
    for (int i = 0; i < 4; ++i)
        #pragma unroll
        for (int j = 0; j < 16; ++j) acc[i][j] = 0.f;

    for (int g = 0; g < 8; ++g) {
        const int ci0 = g * 8;
        __syncthreads();
        for (int idx = t; idx < 3168; idx += 256) {
            const int ci = idx / 396; const int rem = idx - ci * 396;
            const int row = rem / 22; const int col = rem - row * 22;
            const int gr = row - 1, gc = col - 1;
            float v = 0.f;
            if ((unsigned)gr < 16u && (unsigned)gc < 16u)
                v = x[(((size_t)n * 64 + ci0 + ci) << 8) + (gr << 4) + gc];
            xs[idx] = v;
        }
        for (int idx = t; idx < 4608; idx += 256) {
            const int l = idx / 576; const int rem = idx - l * 576;
            const int co = rem / 9; const int k = rem - co * 9;
            ws[l * 576 + k * 64 + co] = w[((ch * 64 + co) * 64 + ci0 + l) * 9 + k];
        }
        __syncthreads();
        for (int l = 0; l < 8; ++l) {
            const float* xci = xs + l * 396;
            const float* wci = ws + l * 576 + 4 * cg;
            #pragma unroll
            for (int ky = 0; ky < 3; ++ky) {
                float wv[3][4];
                #pragma unroll
                for (int kx = 0; kx < 3; ++kx)
                    *reinterpret_cast<float4*>(wv[kx]) =
                        *reinterpret_cast<const float4*>(&wci[(ky * 3 + kx) * 64]);
                #pragma unroll
                for (int rr = 0; rr < 2; ++rr) {
                    const float* rp = xci + (2 * sr + rr + ky) * 22 + 8 * sh;
                    float row[12];
                    #pragma unroll
                    for (int e = 0; e < 6; ++e)
                        *reinterpret_cast<float2*>(&row[2 * e]) =
                            *reinterpret_cast<const float2*>(&rp[2 * e]);
                    #pragma unroll
                    for (int cc = 0; cc < 8; ++cc)
                        #pragma unroll
                        for (int kx = 0; kx < 3; ++kx)
                            #pragma unroll
                            for (int co = 0; co < 4; ++co)
                                acc[co][rr * 8 + cc] = fmaf(row[cc + kx], wv[kx][co], acc[co][rr * 8 + cc]);
                }
            }
        }
    }

    #pragma unroll
    for (int co_l = 0; co_l < 4; ++co_l) {
        const int co = ch * 64 + 4 * cg + co_l;
        const float s = bg[co] * rsqrtf(bv[co] + EPS);
        const float bsv = bb[co] - bm[co] * s;
        #pragma unroll
        for (int pcc = 0; pcc < 4; ++pcc) {
            const float v0 = fmaxf(fmaf(acc[co_l][2 * pcc],     s, bsv), 0.f);
            const float v1 = fmaxf(fmaf(acc[co_l][2 * pcc + 1], s, bsv), 0.f);
            const float v2 = fmaxf(fmaf(acc[co_l][8 + 2 * pcc],     s, bsv), 0.f);
            const float v3 = fmaxf(fmaf(acc[co_l][8 + 2 * pcc + 1], s, bsv), 0.f);
            out[(((size_t)n * 128 + co) * 8 + sr) * 8 + 4 * sh + pcc] =
                fmaxf(fmaxf(v0, v1), fmaxf(v2, v3));
        }
    }
}

// ---------------- FC: [512,8192] @ [256,8192]^T, split-K=8, atomic accumulate ----------------
__global__ __launch_bounds__(256) void k_fc(
    const float* __restrict__ A, const float* __restrict__ Bw, float* __restrict__ C)
{
    __shared__ float As[64][33];
    __shared__ float Bs[64][33];
    const int bm = blockIdx.x, bn = blockIdx.y, kz = blockIdx.z;
    const int t = threadIdx.x;
    const int tm = t >> 4, tn = t & 15;
    float acc[4][4] = {};
    const int k0 = kz * 1024;
    for (int kt = 0; kt < 1024; kt += 32) {
        #pragma unroll
        for (int u = 0; u < 2; ++u) {
            const int f = t + u * 256;
            const int row = f >> 3;
            const int col = (f & 7) * 4;
            const float4 av = *reinterpret_cast<const float4*>(
                &A[(size_t)(bm * 64 + row) * 8192 + k0 + kt + col]);
            As[row][col] = av.x; As[row][col + 1] = av.y;
            As[row][col + 2] = av.z; As[row][col + 3] = av.w;
            const float4 bvv = *reinterpret_cast<const float4*>(
                &Bw[(size_t)(bn * 64 + row) * 8192 + k0 + kt + col]);
            Bs[row][col] = bvv.x; Bs[row][col + 1] = bvv.y;
            Bs[row][col + 2] = bvv.z; Bs[row][col + 3] = bvv.w;
        }
        __syncthreads();
        #pragma unroll
        for (int kk = 0; kk < 32; ++kk) {
            float av[4], bv2[4];
            #pragma unroll
            for (int i = 0; i < 4; ++i) av[i] = As[tm * 4 + i][kk];
            #pragma unroll
            for (int i = 0; i < 4; ++i) bv2[i] = Bs[tn * 4 + i][kk];
            #pragma unroll
            for (int i = 0; i < 4; ++i)
                #pragma unroll
                for (int j = 0; j < 4; ++j)
                    acc[i][j] = fmaf(av[i], bv2[j], acc[i][j]);
        }
        __syncthreads();
    }
    #pragma unroll
    for (int i = 0; i < 4; ++i)
        #pragma unroll
        for (int j = 0; j < 4; ++j)
            atomicAdd(&C[(size_t)(bm * 64 + tm * 4 + i) * 256 + bn * 64 + tn * 4 + j], acc[i][j]);
}

// ---------------- heads ----------------
__global__ __launch_bounds__(128) void k_heads(
    const float* __restrict__ sraw, const float* __restrict__ fcb,
    const float* __restrict__ fg, const float* __restrict__ fb,
    const float* __restrict__ fm, const float* __restrict__ fv,
    const float* __restrict__ cw1, const float* __restrict__ cb1,
    const float* __restrict__ cg, const float* __restrict__ cbb,
    const float* __restrict__ cm, const float* __restrict__ cv,
    const float* __restrict__ cw2, const float* __restrict__ cb2,
    const float* __restrict__ mw1, const float* __restrict__ mb1,
    const float* __restrict__ mg, const float* __restrict__ mbb,
    const float* __restrict__ mm, const float* __restrict__ mv,
    const float* __restrict__ mw2, const float* __restrict__ mb2,
    float* __restrict__ outp)
{
    __shared__ float sv[256];
    const int b = blockIdx.x, t = threadIdx.x;
    for (int k = t; k < 256; k += 128) {
        const float val = sraw[b * 256 + k] + fcb[k];
        const float s = fg[k] * rsqrtf(fv[k] + EPS);
        sv[k] = fmaxf(fmaf(val, s, fb[k] - fm[k] * s), 0.f);
    }
    __syncthreads();
    const int j = t & 63;
    const bool isM = (t >= 64);
    const float* w1  = isM ? mw1 : cw1;
    const float* b1  = isM ? mb1 : cb1;
    const float* g1  = isM ? mg  : cg;
    const float* bb1 = isM ? mbb : cbb;
    const float* m1  = isM ? mm  : cm;
    const float* v1  = isM ? mv  : cv;
    const float* w2  = isM ? mw2 : cw2;
    const float* b2  = isM ? mb2 : cb2;
    float d = 0.f;
    const float* wr = w1 + j * 256;
    #pragma unroll 8
    for (int k = 0; k < 256; ++k) d = fmaf(sv[k], wr[k], d);
    d += b1[j];
    const float s1 = g1[j] * rsqrtf(v1[j] + EPS);
    d = fmaxf(fmaf(d, s1, bb1[j] - m1[j] * s1), 0.f);
    float prod = d * w2[j];
    #pragma unroll
    for (int off = 32; off > 0; off >>= 1) prod += __shfl_down(prod, off);
    if (j == 0) outp[(isM ? 512 : 0) + b] = prod + b2[0];
}

extern "C" void kernel_launch(void* const* d_in, const int* in_sizes, int n_in,
                              void* d_out, int out_size, void* d_ws, size_t ws_size,
                              hipStream_t stream)
{
    const float* x    = (const float*)d_in[0];
    const float* w1   = (const float*)d_in[1];
    const float* bn1g = (const float*)d_in[2];
    const float* bn1b = (const float*)d_in[3];
    const float* bn1m = (const float*)d_in[4];
    const float* bn1v = (const float*)d_in[5];
    const float* w2   = (const float*)d_in[6];
    const float* bn2g = (const float*)d_in[7];
    const float* bn2b = (const float*)d_in[8];
    const float* bn2m = (const float*)d_in[9];
    const float* bn2v = (const float*)d_in[10];
    const float* w3   = (const float*)d_in[11];
    const float* bn3g = (const float*)d_in[12];
    const float* bn3b = (const float*)d_in[13];
    const float* bn3m = (const float*)d_in[14];
    const float* bn3v = (const float*)d_in[15];
    const float* fcw  = (const float*)d_in[16];
    const float* fcb  = (const float*)d_in[17];
    const float* bnfg = (const float*)d_in[18];
    const float* bnfb = (const float*)d_in[19];
    const float* bnfm = (const float*)d_in[20];
    const float* bnfv = (const float*)d_in[21];
    const float* cw1  = (const float*)d_in[22];
    const float* cb1  = (const float*)d_in[23];
    const float* bncg = (const float*)d_in[24];
    const float* bncb = (const float*)d_in[25];
    const float* bncm = (const float*)d_in[26];
    const float* bncv = (const float*)d_in[27];
    const float* cw2  = (const float*)d_in[28];
    const float* cb2  = (const float*)d_in[29];
    const float* mw1  = (const float*)d_in[30];
    const float* mb1  = (const float*)d_in[31];
    const float* bnmg = (const float*)d_in[32];
    const float* bnmb = (const float*)d_in[33];
    const float* bnmm = (const float*)d_in[34];
    const float* bnmv = (const float*)d_in[35];
    const float* mw2  = (const float*)d_in[36];
    const float* mb2  = (const float*)d_in[37];

    float* ws = (float*)d_ws;
    float* h1 = ws;
    float* h2 = h1 + (size_t)512 * 32 * 32 * 32;
    float* h3 = h2 + (size_t)512 * 64 * 16 * 16;
    float* sr = h3 + (size_t)512 * 128 * 8 * 8;
    float* outp = (float*)d_out;

    k_conv1<<<512 * 8, 256, 0, stream>>>(x, w1, bn1g, bn1b, bn1m, bn1v, h1);
    k_conv2<<<512 * 4, 256, 0, stream>>>(h1, w2, bn2g, bn2b, bn2m, bn2v, h2);
    k_conv3<<<512 * 2, 256, 0, stream>>>(h2, w3, bn3g, bn3b, bn3m, bn3v, h3);
    hipMemsetAsync(sr, 0, (size_t)512 * 256 * sizeof(float), stream);
    k_fc<<<dim3(8, 4, 8), 256, 0, stream>>>(h3, fcw, sr);
    k_heads<<<512, 128, 0, stream>>>(sr, fcb, bnfg, bnfb, bnfm, bnfv,
                                     cw1, cb1, bncg, bncb, bncm, bncv, cw2, cb2,
                                     mw1, mb1, bnmg, bnmb, bnmm, bnmv, mw2, mb2, outp);
}

// Round 4
// 289.089 us; speedup vs baseline: 18.6309x; 2.8954x over previous
//
#include <hip/hip_runtime.h>
#include <hip/hip_bf16.h>

#define EPS 1e-5f

typedef __attribute__((ext_vector_type(8))) short bf16x8;
typedef __attribute__((ext_vector_type(4))) float f32x4;

__device__ __forceinline__ ushort f2b(float f) {
    return __builtin_bit_cast(ushort, __float2bfloat16(f));
}
__device__ __forceinline__ bf16x8 ld_frag(const char* p) {
    return __builtin_bit_cast(bf16x8, *reinterpret_cast<const uint4*>(p));
}

// ---------------- prep: pack all weights to bf16 in required layouts ----------------
// w1p [5ky][32co][32k(k=kx*4+ci, kx<5,ci<3 else 0)]
// w2p [9tap][64co][32ci]
// w3p [9tap][128co][64ci]
// fcwp [256j][8192k'] with k' = p*128+c  (source k = c*64+p)
__global__ __launch_bounds__(256) void k_prep(
    const float* __restrict__ w1, const float* __restrict__ w2,
    const float* __restrict__ w3, const float* __restrict__ fcw,
    ushort* __restrict__ w1p, ushort* __restrict__ w2p,
    ushort* __restrict__ w3p, ushort* __restrict__ fcwp)
{
    const int total = 5120 + 18432 + 73728 + 2097152;
    for (int i = blockIdx.x * 256 + threadIdx.x; i < total; i += gridDim.x * 256) {
        if (i < 5120) {
            const int ky = i >> 10, co = (i >> 5) & 31, k = i & 31;
            const int kx = k >> 2, ci = k & 3;
            float v = 0.f;
            if (kx < 5 && ci < 3) v = w1[((co * 3 + ci) * 5 + ky) * 5 + kx];
            w1p[i] = f2b(v);
        } else if (i < 5120 + 18432) {
            const int j = i - 5120;
            const int tap = j >> 11, co = (j >> 5) & 63, ci = j & 31;
            w2p[j] = f2b(w2[(co * 32 + ci) * 9 + tap]);
        } else if (i < 5120 + 18432 + 73728) {
            const int j = i - (5120 + 18432);
            const int tap = j >> 13, co = (j >> 6) & 127, ci = j & 63;
            w3p[j] = f2b(w3[(co * 64 + ci) * 9 + tap]);
        } else {
            const int j = i - (5120 + 18432 + 73728);
            const int jrow = j >> 13, kp = j & 8191;
            const int c = kp & 127, p = kp >> 7;
            fcwp[j] = f2b(fcw[jrow * 8192 + c * 64 + p]);
        }
    }
}

// ---------------- conv1: 5x5 3->32 pad2 +BN+ReLU+pool -> h1 bf16 NHWC [512][32][32][32] ----
// block=(n, q of 8 conv-row strips). 4 waves; wave tile M=128 (2 conv rows) x N=32.
// K = 5 ky-steps of 32 (8 kx-slots x 4 ch).
__global__ __launch_bounds__(256) void k_conv1(
    const float* __restrict__ x, const ushort* __restrict__ w1p,
    const float* __restrict__ bg, const float* __restrict__ bb,
    const float* __restrict__ bm, const float* __restrict__ bv,
    ushort* __restrict__ h1)
{
    __shared__ __align__(16) ushort xs[12 * 72 * 4];   // [row][col(+2)][4ch], 6912 B
    __shared__ __align__(16) ushort ws[5 * 32 * 32];   // [ky][co][k] swz by co, 10240 B
    const int bid = blockIdx.x;
    const int n = bid >> 3, q = bid & 7;
    const int t = threadIdx.x;
    const int wave = t >> 6, lane = t & 63;
    const int g = lane >> 4, l15 = lane & 15;

    // stage input patch (fp32 NCHW -> bf16 packed 4ch)
    for (int idx = t; idx < 864; idx += 256) {
        const int row = idx / 72, col = idx - row * 72;
        const int gr = 8 * q - 2 + row, gc = col - 2;
        ushort p0 = 0, p1 = 0, p2 = 0;
        if ((unsigned)gr < 64u && (unsigned)gc < 64u) {
            const size_t base = ((size_t)n * 3 << 12) + (gr << 6) + gc;
            p0 = f2b(x[base]); p1 = f2b(x[base + 4096]); p2 = f2b(x[base + 8192]);
        }
        ushort4 pk; pk.x = p0; pk.y = p1; pk.z = p2; pk.w = 0;
        *reinterpret_cast<ushort4*>(&xs[idx * 4]) = pk;
    }
    // stage weights (granules of 16B, swizzled by co)  [FIX: 640 granules, was 320]
    for (int i = t; i < 640; i += 256) {
        const int gg = i & 3, r = i >> 2;       // r = ky*32+co, r in [0,160)
        const int co = r & 31;
        const uint4 v = *reinterpret_cast<const uint4*>(&w1p[r * 32 + gg * 8]);
        *reinterpret_cast<uint4*>((char*)ws + r * 64 + ((gg ^ ((co >> 1) & 3)) << 4)) = v;
    }
    __syncthreads();

    f32x4 acc[8][2];
    #pragma unroll
    for (int i = 0; i < 8; ++i) { acc[i][0] = (f32x4){0,0,0,0}; acc[i][1] = (f32x4){0,0,0,0}; }

    const char* xsb = (const char*)xs;
    const char* wsb = (const char*)ws;
    #pragma unroll
    for (int ky = 0; ky < 5; ++ky) {
        bf16x8 a[8], b[2];
        #pragma unroll
        for (int mt = 0; mt < 8; ++mt) {
            const int crl = 2 * wave + (mt >> 2);
            const int ccl = (mt & 3) * 16 + l15;
            const int off = ((crl + ky) * 72 + ccl) * 8 + g * 16;
            const uint2 lo = *reinterpret_cast<const uint2*>(xsb + off);
            const uint2 hi = *reinterpret_cast<const uint2*>(xsb + off + 8);
            uint4 all; all.x = lo.x; all.y = lo.y; all.z = hi.x; all.w = hi.y;
            a[mt] = __builtin_bit_cast(bf16x8, all);
        }
        #pragma unroll
        for (int nt = 0; nt < 2; ++nt) {
            const int co = nt * 16 + l15;
            b[nt] = ld_frag(wsb + (ky * 32 + co) * 64 + ((g ^ ((co >> 1) & 3)) << 4));
        }
        #pragma unroll
        for (int mt = 0; mt < 8; ++mt)
            #pragma unroll
            for (int nt = 0; nt < 2; ++nt)
                acc[mt][nt] = __builtin_amdgcn_mfma_f32_16x16x32_bf16(a[mt], b[nt], acc[mt][nt], 0, 0, 0);
    }

    // epilogue: BN+ReLU+pool(rows mt vs mt+4; regs pairs), write h1 NHWC bf16
    const int prow = q * 4 + wave;
    #pragma unroll
    for (int nt = 0; nt < 2; ++nt) {
        const int co = nt * 16 + l15;
        const float s = bg[co] * rsqrtf(bv[co] + EPS);
        const float bsv = bb[co] - bm[co] * s;
        #pragma unroll
        for (int mt = 0; mt < 4; ++mt) {
            #pragma unroll
            for (int j = 0; j < 2; ++j) {
                const float v0 = fmaxf(fmaf(acc[mt][nt][2 * j],     s, bsv), 0.f);
                const float v1 = fmaxf(fmaf(acc[mt][nt][2 * j + 1], s, bsv), 0.f);
                const float v2 = fmaxf(fmaf(acc[mt + 4][nt][2 * j],     s, bsv), 0.f);
                const float v3 = fmaxf(fmaf(acc[mt + 4][nt][2 * j + 1], s, bsv), 0.f);
                const int ppc = mt * 8 + g * 2 + j;
                h1[(((size_t)n * 32 + prow) * 32 + ppc) * 32 + co] =
                    f2b(fmaxf(fmaxf(v0, v1), fmaxf(v2, v3)));
            }
        }
    }
}

// ---------------- conv2: 3x3 32->64 pad1 +BN+ReLU+pool -> h2 bf16 NHWC [512][16][16][64] ----
// block=(n, q of 4 strips of 8 conv rows). 4 waves; wave M=64 x N=64. K=9 taps x 32ci.
__global__ __launch_bounds__(256) void k_conv2(
    const ushort* __restrict__ h1, const ushort* __restrict__ w2p,
    const float* __restrict__ bg, const float* __restrict__ bb,
    const float* __restrict__ bm, const float* __restrict__ bv,
    ushort* __restrict__ h2)
{
    __shared__ __align__(16) ushort xs[10 * 34 * 32];  // 21760 B, swz by pix
    __shared__ __align__(16) ushort ws[9 * 64 * 32];   // 36864 B, swz by co
    const int bid = blockIdx.x;
    const int n = bid >> 2, q = bid & 3;
    const int t = threadIdx.x;
    const int wave = t >> 6, lane = t & 63;
    const int g = lane >> 4, l15 = lane & 15;

    for (int i = t; i < 1360; i += 256) {
        const int gg = i & 3, pix = i >> 2;
        const int row = pix / 34, col = pix - row * 34;
        const int gr = 8 * q - 1 + row, gc = col - 1;
        uint4 v = {0, 0, 0, 0};
        if ((unsigned)gr < 32u && (unsigned)gc < 32u)
            v = *reinterpret_cast<const uint4*>(&h1[((((size_t)n * 32 + gr) * 32 + gc) << 5) + gg * 8]);
        *reinterpret_cast<uint4*>((char*)xs + pix * 64 + ((gg ^ ((pix >> 1) & 3)) << 4)) = v;
    }
    for (int i = t; i < 2304; i += 256) {
        const int gg = i & 3, r = i >> 2;   // r = tap*64+co
        const int co = r & 63;
        const uint4 v = *reinterpret_cast<const uint4*>(&w2p[r * 32 + gg * 8]);
        *reinterpret_cast<uint4*>((char*)ws + r * 64 + ((gg ^ ((co >> 1) & 3)) << 4)) = v;
    }
    __syncthreads();

    f32x4 acc[4][4];
    #pragma unroll
    for (int i = 0; i < 4; ++i)
        #pragma unroll
        for (int j = 0; j < 4; ++j) acc[i][j] = (f32x4){0,0,0,0};

    const char* xsb = (const char*)xs;
    const char* wsb = (const char*)ws;
    #pragma unroll
    for (int tap = 0; tap < 9; ++tap) {
        const int ky = tap / 3, kx = tap - 3 * ky;
        bf16x8 a[4], b[4];
        #pragma unroll
        for (int mt = 0; mt < 4; ++mt) {
            const int crl = 2 * wave + (mt >> 1);
            const int ccl = (mt & 1) * 16 + l15;
            const int pix = (crl + ky) * 34 + ccl + kx;
            a[mt] = ld_frag(xsb + pix * 64 + ((g ^ ((pix >> 1) & 3)) << 4));
        }
        #pragma unroll
        for (int nt = 0; nt < 4; ++nt) {
            const int co = nt * 16 + l15;
            b[nt] = ld_frag(wsb + (tap * 64 + co) * 64 + ((g ^ ((co >> 1) & 3)) << 4));
        }
        #pragma unroll
        for (int mt = 0; mt < 4; ++mt)
            #pragma unroll
            for (int nt = 0; nt < 4; ++nt)
                acc[mt][nt] = __builtin_amdgcn_mfma_f32_16x16x32_bf16(a[mt], b[nt], acc[mt][nt], 0, 0, 0);
    }
    __syncthreads();

    const int prow = q * 4 + wave;
    #pragma unroll
    for (int nt = 0; nt < 4; ++nt) {
        const int co = nt * 16 + l15;
        const float s = bg[co] * rsqrtf(bv[co] + EPS);
        const float bsv = bb[co] - bm[co] * s;
        #pragma unroll
        for (int mtl = 0; mtl < 2; ++mtl) {
            #pragma unroll
            for (int j = 0; j < 2; ++j) {
                const float v0 = fmaxf(fmaf(acc[mtl][nt][2 * j],     s, bsv), 0.f);
                const float v1 = fmaxf(fmaf(acc[mtl][nt][2 * j + 1], s, bsv), 0.f);
                const float v2 = fmaxf(fmaf(acc[mtl + 2][nt][2 * j],     s, bsv), 0.f);
                const float v3 = fmaxf(fmaf(acc[mtl + 2][nt][2 * j + 1], s, bsv), 0.f);
                const int ppc = mtl * 8 + g * 2 + j;
                h2[(((size_t)n * 16 + prow) * 16 + ppc) * 64 + co] =
                    f2b(fmaxf(fmaxf(v0, v1), fmaxf(v2, v3)));
            }
        }
    }
}

// ---------------- conv3: 3x3 64->128 pad1 +BN+ReLU+pool -> h3 bf16 NHWC [512][8][8][128] ----
// block=(n, co-half). 4 waves; wave M=64 (4 pixel rows) x N=64. 2 ci-halves x 9 taps x K32.
__global__ __launch_bounds__(256) void k_conv3(
    const ushort* __restrict__ h2, const ushort* __restrict__ w3p,
    const float* __restrict__ bg, const float* __restrict__ bb,
    const float* __restrict__ bm, const float* __restrict__ bv,
    ushort* __restrict__ h3)
{
    __shared__ __align__(16) ushort xs[18 * 18 * 32];  // 20736 B
    __shared__ __align__(16) ushort ws[9 * 64 * 32];   // 36864 B
    const int bid = blockIdx.x;
    const int n = bid >> 1, ch = bid & 1;
    const int t = threadIdx.x;
    const int wave = t >> 6, lane = t & 63;
    const int g = lane >> 4, l15 = lane & 15;

    f32x4 acc[4][4];
    #pragma unroll
    for (int i = 0; i < 4; ++i)
        #pragma unroll
        for (int j = 0; j < 4; ++j) acc[i][j] = (f32x4){0,0,0,0};

    const char* xsb = (const char*)xs;
    const char* wsb = (const char*)ws;

    for (int gci = 0; gci < 2; ++gci) {
        if (gci) __syncthreads();
        for (int i = t; i < 1296; i += 256) {
            const int gg = i & 3, pix = i >> 2;
            const int row = pix / 18, col = pix - row * 18;
            const int gr = row - 1, gc = col - 1;
            uint4 v = {0, 0, 0, 0};
            if ((unsigned)gr < 16u && (unsigned)gc < 16u)
                v = *reinterpret_cast<const uint4*>(
                    &h2[((((size_t)n * 16 + gr) * 16 + gc) << 6) + gci * 32 + gg * 8]);
            *reinterpret_cast<uint4*>((char*)xs + pix * 64 + ((gg ^ ((pix >> 1) & 3)) << 4)) = v;
        }
        for (int i = t; i < 2304; i += 256) {
            const int gg = i & 3, r = i >> 2;   // r = tap*64+co_local
            const int tap = r >> 6, co = r & 63;
            const uint4 v = *reinterpret_cast<const uint4*>(
                &w3p[((size_t)(tap * 128 + ch * 64 + co) << 6) + gci * 32 + gg * 8]);
            *reinterpret_cast<uint4*>((char*)ws + r * 64 + ((gg ^ ((co >> 1) & 3)) << 4)) = v;
        }
        __syncthreads();
        #pragma unroll
        for (int tap = 0; tap < 9; ++tap) {
            const int ky = tap / 3, kx = tap - 3 * ky;
            bf16x8 a[4], b[4];
            #pragma unroll
            for (int mt = 0; mt < 4; ++mt) {
                const int pr = 4 * wave + mt;
                const int pix = (pr + ky) * 18 + l15 + kx;
                a[mt] = ld_frag(xsb + pix * 64 + ((g ^ ((pix >> 1) & 3)) << 4));
            }
            #pragma unroll
            for (int nt = 0; nt < 4; ++nt) {
                const int co = nt * 16 + l15;
                b[nt] = ld_frag(wsb + (tap * 64 + co) * 64 + ((g ^ ((co >> 1) & 3)) << 4));
            }
            #pragma unroll
            for (int mt = 0; mt < 4; ++mt)
                #pragma unroll
                for (int nt = 0; nt < 4; ++nt)
                    acc[mt][nt] = __builtin_amdgcn_mfma_f32_16x16x32_bf16(a[mt], b[nt], acc[mt][nt], 0, 0, 0);
        }
    }

    #pragma unroll
    for (int nt = 0; nt < 4; ++nt) {
        const int co = ch * 64 + nt * 16 + l15;
        const float s = bg[co] * rsqrtf(bv[co] + EPS);
        const float bsv = bb[co] - bm[co] * s;
        #pragma unroll
        for (int mtl = 0; mtl < 2; ++mtl) {
            #pragma unroll
            for (int j = 0; j < 2; ++j) {
                const int mt = mtl * 2;
                const float v0 = fmaxf(fmaf(acc[mt][nt][2 * j],     s, bsv), 0.f);
                const float v1 = fmaxf(fmaf(acc[mt][nt][2 * j + 1], s, bsv), 0.f);
                const float v2 = fmaxf(fmaf(acc[mt + 1][nt][2 * j],     s, bsv), 0.f);
                const float v3 = fmaxf(fmaf(acc[mt + 1][nt][2 * j + 1], s, bsv), 0.f);
                const int ppr = 2 * wave + mtl;
                const int ppc = g * 2 + j;
                h3[(((size_t)n * 8 + ppr) * 8 + ppc) * 128 + co] =
                    f2b(fmaxf(fmaxf(v0, v1), fmaxf(v2, v3)));
            }
        }
    }
}

// ---------------- FC: [512,8192]bf16 @ fcwp[256,8192]bf16^T, split-K, atomic fp32 ----------------
// grid (bm2, bn2, kz8), 512 thr = 8 waves (4m x 2n). Wave M=64 x N=64. K-chunk 1024.
__global__ __launch_bounds__(512) void k_fc(
    const ushort* __restrict__ A, const ushort* __restrict__ Bw, float* __restrict__ C)
{
    __shared__ __align__(16) ushort As[256 * 32];  // 16 KB
    __shared__ __align__(16) ushort Bs[128 * 32];  // 8 KB
    const int bm = blockIdx.x, bn = blockIdx.y, kz = blockIdx.z;
    const int t = threadIdx.x;
    const int wave = t >> 6, lane = t & 63;
    const int wm = wave >> 1, wn = wave & 1;
    const int g = lane >> 4, l15 = lane & 15;

    f32x4 acc[4][4];
    #pragma unroll
    for (int i = 0; i < 4; ++i)
        #pragma unroll
        for (int j = 0; j < 4; ++j) acc[i][j] = (f32x4){0,0,0,0};

    const char* asb = (const char*)As;
    const char* bsb = (const char*)Bs;
    for (int kk = 0; kk < 32; ++kk) {
        const int k0 = kz * 1024 + kk * 32;
        if (kk) __syncthreads();
        for (int i = t; i < 1536; i += 512) {
            const int gg = i & 3, row = (i >> 2);
            if (row < 256) {
                const uint4 v = *reinterpret_cast<const uint4*>(
                    &A[(size_t)(bm * 256 + row) * 8192 + k0 + gg * 8]);
                *reinterpret_cast<uint4*>((char*)As + row * 64 + ((gg ^ ((row >> 1) & 3)) << 4)) = v;
            } else {
                const int rw = row - 256;
                const uint4 v = *reinterpret_cast<const uint4*>(
                    &Bw[(size_t)(bn * 128 + rw) * 8192 + k0 + gg * 8]);
                *reinterpret_cast<uint4*>((char*)Bs + rw * 64 + ((gg ^ ((rw >> 1) & 3)) << 4)) = v;
            }
        }
        __syncthreads();
        bf16x8 a[4], b[4];
        #pragma unroll
        for (int mt = 0; mt < 4; ++mt) {
            const int r = wm * 64 + mt * 16 + l15;
            a[mt] = ld_frag(asb + r * 64 + ((g ^ ((r >> 1) & 3)) << 4));
        }
        #pragma unroll
        for (int nt = 0; nt < 4; ++nt) {
            const int r = wn * 64 + nt * 16 + l15;
            b[nt] = ld_frag(bsb + r * 64 + ((g ^ ((r >> 1) & 3)) << 4));
        }
        #pragma unroll
        for (int mt = 0; mt < 4; ++mt)
            #pragma unroll
            for (int nt = 0; nt < 4; ++nt)
                acc[mt][nt] = __builtin_amdgcn_mfma_f32_16x16x32_bf16(a[mt], b[nt], acc[mt][nt], 0, 0, 0);
    }

    #pragma unroll
    for (int mt = 0; mt < 4; ++mt) {
        #pragma unroll
        for (int nt = 0; nt < 4; ++nt) {
            const int col = bn * 128 + wn * 64 + nt * 16 + l15;
            #pragma unroll
            for (int r = 0; r < 4; ++r) {
                const int row = bm * 256 + wm * 64 + mt * 16 + g * 4 + r;
                atomicAdd(&C[(size_t)row * 256 + col], acc[mt][nt][r]);
            }
        }
    }
}

// ---------------- heads ----------------
__global__ __launch_bounds__(128) void k_heads(
    const float* __restrict__ sraw, const float* __restrict__ fcb,
    const float* __restrict__ fg, const float* __restrict__ fb,
    const float* __restrict__ fm, const float* __restrict__ fv,
    const float* __restrict__ cw1, const float* __restrict__ cb1,
    const float* __restrict__ cg, const float* __restrict__ cbb,
    const float* __restrict__ cm, const float* __restrict__ cv,
    const float* __restrict__ cw2, const float* __restrict__ cb2,
    const float* __restrict__ mw1, const float* __restrict__ mb1,
    const float* __restrict__ mg, const float* __restrict__ mbb,
    const float* __restrict__ mm, const float* __restrict__ mv,
    const float* __restrict__ mw2, const float* __restrict__ mb2,
    float* __restrict__ outp)
{
    __shared__ float sv[256];
    const int b = blockIdx.x, t = threadIdx.x;
    for (int k = t; k < 256; k += 128) {
        const float val = sraw[b * 256 + k] + fcb[k];
        const float s = fg[k] * rsqrtf(fv[k] + EPS);
        sv[k] = fmaxf(fmaf(val, s, fb[k] - fm[k] * s), 0.f);
    }
    __syncthreads();
    const int j = t & 63;
    const bool isM = (t >= 64);
    const float* w1  = isM ? mw1 : cw1;
    const float* b1  = isM ? mb1 : cb1;
    const float* g1  = isM ? mg  : cg;
    const float* bb1 = isM ? mbb : cbb;
    const float* m1  = isM ? mm  : cm;
    const float* v1  = isM ? mv  : cv;
    const float* w2  = isM ? mw2 : cw2;
    const float* b2  = isM ? mb2 : cb2;
    float d = 0.f;
    const float* wr = w1 + j * 256;
    #pragma unroll 8
    for (int k = 0; k < 256; ++k) d = fmaf(sv[k], wr[k], d);
    d += b1[j];
    const float s1 = g1[j] * rsqrtf(v1[j] + EPS);
    d = fmaxf(fmaf(d, s1, bb1[j] - m1[j] * s1), 0.f);
    float prod = d * w2[j];
    #pragma unroll
    for (int off = 32; off > 0; off >>= 1) prod += __shfl_down(prod, off);
    if (j == 0) outp[(isM ? 512 : 0) + b] = prod + b2[0];
}

extern "C" void kernel_launch(void* const* d_in, const int* in_sizes, int n_in,
                              void* d_out, int out_size, void* d_ws, size_t ws_size,
                              hipStream_t stream)
{
    const float* x    = (const float*)d_in[0];
    const float* w1   = (const float*)d_in[1];
    const float* bn1g = (const float*)d_in[2];
    const float* bn1b = (const float*)d_in[3];
    const float* bn1m = (const float*)d_in[4];
    const float* bn1v = (const float*)d_in[5];
    const float* w2   = (const float*)d_in[6];
    const float* bn2g = (const float*)d_in[7];
    const float* bn2b = (const float*)d_in[8];
    const float* bn2m = (const float*)d_in[9];
    const float* bn2v = (const float*)d_in[10];
    const float* w3   = (const float*)d_in[11];
    const float* bn3g = (const float*)d_in[12];
    const float* bn3b = (const float*)d_in[13];
    const float* bn3m = (const float*)d_in[14];
    const float* bn3v = (const float*)d_in[15];
    const float* fcw  = (const float*)d_in[16];
    const float* fcb  = (const float*)d_in[17];
    const float* bnfg = (const float*)d_in[18];
    const float* bnfb = (const float*)d_in[19];
    const float* bnfm = (const float*)d_in[20];
    const float* bnfv = (const float*)d_in[21];
    const float* cw1  = (const float*)d_in[22];
    const float* cb1  = (const float*)d_in[23];
    const float* bncg = (const float*)d_in[24];
    const float* bncb = (const float*)d_in[25];
    const float* bncm = (const float*)d_in[26];
    const float* bncv = (const float*)d_in[27];
    const float* cw2  = (const float*)d_in[28];
    const float* cb2  = (const float*)d_in[29];
    const float* mw1  = (const float*)d_in[30];
    const float* mb1  = (const float*)d_in[31];
    const float* bnmg = (const float*)d_in[32];
    const float* bnmb = (const float*)d_in[33];
    const float* bnmm = (const float*)d_in[34];
    const float* bnmv = (const float*)d_in[35];
    const float* mw2  = (const float*)d_in[36];
    const float* mb2  = (const float*)d_in[37];

    char* W = (char*)d_ws;
    ushort* h1   = (ushort*)(W);
    ushort* h2   = (ushort*)(W + 33554432);
    ushort* h3   = (ushort*)(W + 50331648);
    float*  sr   = (float*) (W + 58720256);
    ushort* w1p  = (ushort*)(W + 59244544);
    ushort* w2p  = (ushort*)(W + 59254784);
    ushort* w3p  = (ushort*)(W + 59291648);
    ushort* fcwp = (ushort*)(W + 59439104);
    float* outp = (float*)d_out;

    k_prep<<<2048, 256, 0, stream>>>(w1, w2, w3, fcw, w1p, w2p, w3p, fcwp);
    k_conv1<<<512 * 8, 256, 0, stream>>>(x, w1p, bn1g, bn1b, bn1m, bn1v, h1);
    k_conv2<<<512 * 4, 256, 0, stream>>>(h1, w2p, bn2g, bn2b, bn2m, bn2v, h2);
    k_conv3<<<512 * 2, 256, 0, stream>>>(h2, w3p, bn3g, bn3b, bn3m, bn3v, h3);
    hipMemsetAsync(sr, 0, (size_t)512 * 256 * sizeof(float), stream);
    k_fc<<<dim3(2, 2, 8), 512, 0, stream>>>(h3, fcwp, sr);
    k_heads<<<512, 128, 0, stream>>>(sr, fcb, bnfg, bnfb, bnfm, bnfv,
                                     cw1, cb1, bncg, bncb, bncm, bncv, cw2, cb2,
                                     mw1, mb1, bnmg, bnmb, bnmm, bnmv, mw2, mb2, outp);
}

// Round 5
// 254.441 us; speedup vs baseline: 21.1679x; 1.1362x over previous
//
#include <hip/hip_runtime.h>
#include <hip/hip_bf16.h>

#define EPS 1e-5f

typedef __attribute__((ext_vector_type(8))) short bf16x8;
typedef __attribute__((ext_vector_type(4))) float f32x4;

__device__ __forceinline__ ushort f2b(float f) {
    return __builtin_bit_cast(ushort, __float2bfloat16(f));
}
__device__ __forceinline__ bf16x8 ld_frag(const char* p) {
    return __builtin_bit_cast(bf16x8, *reinterpret_cast<const uint4*>(p));
}

// ---------------- prep: pack conv weights to bf16 ----------------
// w1p [5ky][32co][32k(k=kx*4+ci, kx<5,ci<3 else 0)]
// w2p [9tap][64co][32ci]
// w3p [9tap][128co][64ci]
__global__ __launch_bounds__(256) void k_prep(
    const float* __restrict__ w1, const float* __restrict__ w2,
    const float* __restrict__ w3,
    ushort* __restrict__ w1p, ushort* __restrict__ w2p, ushort* __restrict__ w3p)
{
    const int total = 5120 + 18432 + 73728;
    for (int i = blockIdx.x * 256 + threadIdx.x; i < total; i += gridDim.x * 256) {
        if (i < 5120) {
            const int ky = i >> 10, co = (i >> 5) & 31, k = i & 31;
            const int kx = k >> 2, ci = k & 3;
            float v = 0.f;
            if (kx < 5 && ci < 3) v = w1[((co * 3 + ci) * 5 + ky) * 5 + kx];
            w1p[i] = f2b(v);
        } else if (i < 5120 + 18432) {
            const int j = i - 5120;
            const int tap = j >> 11, co = (j >> 5) & 63, ci = j & 31;
            w2p[j] = f2b(w2[(co * 32 + ci) * 9 + tap]);
        } else {
            const int j = i - (5120 + 18432);
            const int tap = j >> 13, co = (j >> 6) & 127, ci = j & 63;
            w3p[j] = f2b(w3[(co * 64 + ci) * 9 + tap]);
        }
    }
}

// ---------------- prep_fc: fcw [256][8192] fp32 -> fcwp [256][8192] bf16 with k'=p*128+c ----
// One block per output row j; coalesced read, LDS transpose (pad 66), coalesced write.
__global__ __launch_bounds__(256) void k_prep_fc(
    const float* __restrict__ fcw, ushort* __restrict__ fcwp)
{
    __shared__ ushort l[128 * 66];
    const int j = blockIdx.x, t = threadIdx.x;
    const float* src = fcw + (size_t)j * 8192;
    #pragma unroll
    for (int i = 0; i < 32; ++i) {
        const int idx = i * 256 + t;          // source k = c*64+p (linear)
        const int c = idx >> 6, p = idx & 63;
        l[c * 66 + p] = f2b(src[idx]);
    }
    __syncthreads();
    ushort* dst = fcwp + (size_t)j * 8192;
    #pragma unroll
    for (int i = 0; i < 32; ++i) {
        const int idx = i * 256 + t;          // dest k' = p*128+c (linear)
        const int c = idx & 127, p = idx >> 7;
        dst[idx] = l[c * 66 + p];
    }
}

// ---------------- conv1: 5x5 3->32 pad2 +BN+ReLU+pool -> h1 bf16 NHWC [512][32][32][32] ----
__global__ __launch_bounds__(256) void k_conv1(
    const float* __restrict__ x, const ushort* __restrict__ w1p,
    const float* __restrict__ bg, const float* __restrict__ bb,
    const float* __restrict__ bm, const float* __restrict__ bv,
    ushort* __restrict__ h1)
{
    __shared__ __align__(16) ushort xs[12 * 72 * 4];
    __shared__ __align__(16) ushort ws[5 * 32 * 32];
    const int bid = blockIdx.x;
    const int n = bid >> 3, q = bid & 7;
    const int t = threadIdx.x;
    const int wave = t >> 6, lane = t & 63;
    const int g = lane >> 4, l15 = lane & 15;

    for (int idx = t; idx < 864; idx += 256) {
        const int row = idx / 72, col = idx - row * 72;
        const int gr = 8 * q - 2 + row, gc = col - 2;
        ushort p0 = 0, p1 = 0, p2 = 0;
        if ((unsigned)gr < 64u && (unsigned)gc < 64u) {
            const size_t base = ((size_t)n * 3 << 12) + (gr << 6) + gc;
            p0 = f2b(x[base]); p1 = f2b(x[base + 4096]); p2 = f2b(x[base + 8192]);
        }
        ushort4 pk; pk.x = p0; pk.y = p1; pk.z = p2; pk.w = 0;
        *reinterpret_cast<ushort4*>(&xs[idx * 4]) = pk;
    }
    for (int i = t; i < 640; i += 256) {
        const int gg = i & 3, r = i >> 2;
        const int co = r & 31;
        const uint4 v = *reinterpret_cast<const uint4*>(&w1p[r * 32 + gg * 8]);
        *reinterpret_cast<uint4*>((char*)ws + r * 64 + ((gg ^ ((co >> 1) & 3)) << 4)) = v;
    }
    __syncthreads();

    f32x4 acc[8][2];
    #pragma unroll
    for (int i = 0; i < 8; ++i) { acc[i][0] = (f32x4){0,0,0,0}; acc[i][1] = (f32x4){0,0,0,0}; }

    const char* xsb = (const char*)xs;
    const char* wsb = (const char*)ws;
    #pragma unroll
    for (int ky = 0; ky < 5; ++ky) {
        bf16x8 a[8], b[2];
        #pragma unroll
        for (int mt = 0; mt < 8; ++mt) {
            const int crl = 2 * wave + (mt >> 2);
            const int ccl = (mt & 3) * 16 + l15;
            const int off = ((crl + ky) * 72 + ccl) * 8 + g * 16;
            const uint2 lo = *reinterpret_cast<const uint2*>(xsb + off);
            const uint2 hi = *reinterpret_cast<const uint2*>(xsb + off + 8);
            uint4 all; all.x = lo.x; all.y = lo.y; all.z = hi.x; all.w = hi.y;
            a[mt] = __builtin_bit_cast(bf16x8, all);
        }
        #pragma unroll
        for (int nt = 0; nt < 2; ++nt) {
            const int co = nt * 16 + l15;
            b[nt] = ld_frag(wsb + (ky * 32 + co) * 64 + ((g ^ ((co >> 1) & 3)) << 4));
        }
        #pragma unroll
        for (int mt = 0; mt < 8; ++mt)
            #pragma unroll
            for (int nt = 0; nt < 2; ++nt)
                acc[mt][nt] = __builtin_amdgcn_mfma_f32_16x16x32_bf16(a[mt], b[nt], acc[mt][nt], 0, 0, 0);
    }

    const int prow = q * 4 + wave;
    #pragma unroll
    for (int nt = 0; nt < 2; ++nt) {
        const int co = nt * 16 + l15;
        const float s = bg[co] * rsqrtf(bv[co] + EPS);
        const float bsv = bb[co] - bm[co] * s;
        #pragma unroll
        for (int mt = 0; mt < 4; ++mt) {
            #pragma unroll
            for (int j = 0; j < 2; ++j) {
                const float v0 = fmaxf(fmaf(acc[mt][nt][2 * j],     s, bsv), 0.f);
                const float v1 = fmaxf(fmaf(acc[mt][nt][2 * j + 1], s, bsv), 0.f);
                const float v2 = fmaxf(fmaf(acc[mt + 4][nt][2 * j],     s, bsv), 0.f);
                const float v3 = fmaxf(fmaf(acc[mt + 4][nt][2 * j + 1], s, bsv), 0.f);
                const int ppc = mt * 8 + g * 2 + j;
                h1[(((size_t)n * 32 + prow) * 32 + ppc) * 32 + co] =
                    f2b(fmaxf(fmaxf(v0, v1), fmaxf(v2, v3)));
            }
        }
    }
}

// ---------------- conv2: 3x3 32->64 pad1 +BN+ReLU+pool -> h2 bf16 NHWC [512][16][16][64] ----
__global__ __launch_bounds__(256) void k_conv2(
    const ushort* __restrict__ h1, const ushort* __restrict__ w2p,
    const float* __restrict__ bg, const float* __restrict__ bb,
    const float* __restrict__ bm, const float* __restrict__ bv,
    ushort* __restrict__ h2)
{
    __shared__ __align__(16) ushort xs[10 * 34 * 32];
    __shared__ __align__(16) ushort ws[9 * 64 * 32];
    const int bid = blockIdx.x;
    const int n = bid >> 2, q = bid & 3;
    const int t = threadIdx.x;
    const int wave = t >> 6, lane = t & 63;
    const int g = lane >> 4, l15 = lane & 15;

    for (int i = t; i < 1360; i += 256) {
        const int gg = i & 3, pix = i >> 2;
        const int row = pix / 34, col = pix - row * 34;
        const int gr = 8 * q - 1 + row, gc = col - 1;
        uint4 v = {0, 0, 0, 0};
        if ((unsigned)gr < 32u && (unsigned)gc < 32u)
            v = *reinterpret_cast<const uint4*>(&h1[((((size_t)n * 32 + gr) * 32 + gc) << 5) + gg * 8]);
        *reinterpret_cast<uint4*>((char*)xs + pix * 64 + ((gg ^ ((pix >> 1) & 3)) << 4)) = v;
    }
    for (int i = t; i < 2304; i += 256) {
        const int gg = i & 3, r = i >> 2;
        const int co = r & 63;
        const uint4 v = *reinterpret_cast<const uint4*>(&w2p[r * 32 + gg * 8]);
        *reinterpret_cast<uint4*>((char*)ws + r * 64 + ((gg ^ ((co >> 1) & 3)) << 4)) = v;
    }
    __syncthreads();

    f32x4 acc[4][4];
    #pragma unroll
    for (int i = 0; i < 4; ++i)
        #pragma unroll
        for (int j = 0; j < 4; ++j) acc[i][j] = (f32x4){0,0,0,0};

    const char* xsb = (const char*)xs;
    const char* wsb = (const char*)ws;
    #pragma unroll
    for (int tap = 0; tap < 9; ++tap) {
        const int ky = tap / 3, kx = tap - 3 * ky;
        bf16x8 a[4], b[4];
        #pragma unroll
        for (int mt = 0; mt < 4; ++mt) {
            const int crl = 2 * wave + (mt >> 1);
            const int ccl = (mt & 1) * 16 + l15;
            const int pix = (crl + ky) * 34 + ccl + kx;
            a[mt] = ld_frag(xsb + pix * 64 + ((g ^ ((pix >> 1) & 3)) << 4));
        }
        #pragma unroll
        for (int nt = 0; nt < 4; ++nt) {
            const int co = nt * 16 + l15;
            b[nt] = ld_frag(wsb + (tap * 64 + co) * 64 + ((g ^ ((co >> 1) & 3)) << 4));
        }
        #pragma unroll
        for (int mt = 0; mt < 4; ++mt)
            #pragma unroll
            for (int nt = 0; nt < 4; ++nt)
                acc[mt][nt] = __builtin_amdgcn_mfma_f32_16x16x32_bf16(a[mt], b[nt], acc[mt][nt], 0, 0, 0);
    }
    __syncthreads();

    const int prow = q * 4 + wave;
    #pragma unroll
    for (int nt = 0; nt < 4; ++nt) {
        const int co = nt * 16 + l15;
        const float s = bg[co] * rsqrtf(bv[co] + EPS);
        const float bsv = bb[co] - bm[co] * s;
        #pragma unroll
        for (int mtl = 0; mtl < 2; ++mtl) {
            #pragma unroll
            for (int j = 0; j < 2; ++j) {
                const float v0 = fmaxf(fmaf(acc[mtl][nt][2 * j],     s, bsv), 0.f);
                const float v1 = fmaxf(fmaf(acc[mtl][nt][2 * j + 1], s, bsv), 0.f);
                const float v2 = fmaxf(fmaf(acc[mtl + 2][nt][2 * j],     s, bsv), 0.f);
                const float v3 = fmaxf(fmaf(acc[mtl + 2][nt][2 * j + 1], s, bsv), 0.f);
                const int ppc = mtl * 8 + g * 2 + j;
                h2[(((size_t)n * 16 + prow) * 16 + ppc) * 64 + co] =
                    f2b(fmaxf(fmaxf(v0, v1), fmaxf(v2, v3)));
            }
        }
    }
}

// ---------------- conv3: 3x3 64->128 pad1 +BN+ReLU+pool -> h3 bf16 NHWC [512][8][8][128] ----
__global__ __launch_bounds__(256) void k_conv3(
    const ushort* __restrict__ h2, const ushort* __restrict__ w3p,
    const float* __restrict__ bg, const float* __restrict__ bb,
    const float* __restrict__ bm, const float* __restrict__ bv,
    ushort* __restrict__ h3)
{
    __shared__ __align__(16) ushort xs[18 * 18 * 32];
    __shared__ __align__(16) ushort ws[9 * 64 * 32];
    const int bid = blockIdx.x;
    const int n = bid >> 1, ch = bid & 1;
    const int t = threadIdx.x;
    const int wave = t >> 6, lane = t & 63;
    const int g = lane >> 4, l15 = lane & 15;

    f32x4 acc[4][4];
    #pragma unroll
    for (int i = 0; i < 4; ++i)
        #pragma unroll
        for (int j = 0; j < 4; ++j) acc[i][j] = (f32x4){0,0,0,0};

    const char* xsb = (const char*)xs;
    const char* wsb = (const char*)ws;

    for (int gci = 0; gci < 2; ++gci) {
        if (gci) __syncthreads();
        for (int i = t; i < 1296; i += 256) {
            const int gg = i & 3, pix = i >> 2;
            const int row = pix / 18, col = pix - row * 18;
            const int gr = row - 1, gc = col - 1;
            uint4 v = {0, 0, 0, 0};
            if ((unsigned)gr < 16u && (unsigned)gc < 16u)
                v = *reinterpret_cast<const uint4*>(
                    &h2[((((size_t)n * 16 + gr) * 16 + gc) << 6) + gci * 32 + gg * 8]);
            *reinterpret_cast<uint4*>((char*)xs + pix * 64 + ((gg ^ ((pix >> 1) & 3)) << 4)) = v;
        }
        for (int i = t; i < 2304; i += 256) {
            const int gg = i & 3, r = i >> 2;
            const int tap = r >> 6, co = r & 63;
            const uint4 v = *reinterpret_cast<const uint4*>(
                &w3p[((size_t)(tap * 128 + ch * 64 + co) << 6) + gci * 32 + gg * 8]);
            *reinterpret_cast<uint4*>((char*)ws + r * 64 + ((gg ^ ((co >> 1) & 3)) << 4)) = v;
        }
        __syncthreads();
        #pragma unroll
        for (int tap = 0; tap < 9; ++tap) {
            const int ky = tap / 3, kx = tap - 3 * ky;
            bf16x8 a[4], b[4];
            #pragma unroll
            for (int mt = 0; mt < 4; ++mt) {
                const int pr = 4 * wave + mt;
                const int pix = (pr + ky) * 18 + l15 + kx;
                a[mt] = ld_frag(xsb + pix * 64 + ((g ^ ((pix >> 1) & 3)) << 4));
            }
            #pragma unroll
            for (int nt = 0; nt < 4; ++nt) {
                const int co = nt * 16 + l15;
                b[nt] = ld_frag(wsb + (tap * 64 + co) * 64 + ((g ^ ((co >> 1) & 3)) << 4));
            }
            #pragma unroll
            for (int mt = 0; mt < 4; ++mt)
                #pragma unroll
                for (int nt = 0; nt < 4; ++nt)
                    acc[mt][nt] = __builtin_amdgcn_mfma_f32_16x16x32_bf16(a[mt], b[nt], acc[mt][nt], 0, 0, 0);
        }
    }

    #pragma unroll
    for (int nt = 0; nt < 4; ++nt) {
        const int co = ch * 64 + nt * 16 + l15;
        const float s = bg[co] * rsqrtf(bv[co] + EPS);
        const float bsv = bb[co] - bm[co] * s;
        #pragma unroll
        for (int mtl = 0; mtl < 2; ++mtl) {
            #pragma unroll
            for (int j = 0; j < 2; ++j) {
                const int mt = mtl * 2;
                const float v0 = fmaxf(fmaf(acc[mt][nt][2 * j],     s, bsv), 0.f);
                const float v1 = fmaxf(fmaf(acc[mt][nt][2 * j + 1], s, bsv), 0.f);
                const float v2 = fmaxf(fmaf(acc[mt + 1][nt][2 * j],     s, bsv), 0.f);
                const float v3 = fmaxf(fmaf(acc[mt + 1][nt][2 * j + 1], s, bsv), 0.f);
                const int ppr = 2 * wave + mtl;
                const int ppc = g * 2 + j;
                h3[(((size_t)n * 8 + ppr) * 8 + ppc) * 128 + co] =
                    f2b(fmaxf(fmaxf(v0, v1), fmaxf(v2, v3)));
            }
        }
    }
}

// ---------------- FC: [512,8192]bf16 @ fcwp[256,8192]bf16^T -> partials sr[16][512][256] ----
// grid (8 bm, 4 bn, 16 kz), 256 thr = 4 waves; block tile 64x64, K-chunk 512.
// Wave w owns N16 slice w*16; per k-step: 4 a-frags (shared rows) + 1 b-frag, 4 MFMA.
__global__ __launch_bounds__(256) void k_fc(
    const ushort* __restrict__ A, const ushort* __restrict__ Bw, float* __restrict__ C)
{
    __shared__ __align__(16) ushort As[64 * 32];
    __shared__ __align__(16) ushort Bs[64 * 32];
    const int bm = blockIdx.x, bn = blockIdx.y, kz = blockIdx.z;
    const int t = threadIdx.x;
    const int wave = t >> 6, lane = t & 63;
    const int g = lane >> 4, l15 = lane & 15;

    f32x4 acc[4];
    #pragma unroll
    for (int i = 0; i < 4; ++i) acc[i] = (f32x4){0,0,0,0};

    const char* asb = (const char*)As;
    const char* bsb = (const char*)Bs;
    for (int kk = 0; kk < 16; ++kk) {
        const int k0 = kz * 512 + kk * 32;
        if (kk) __syncthreads();
        {
            const int gg = t & 3, row = t >> 2;   // 256 threads -> 64 rows x 4 granules
            const uint4 va = *reinterpret_cast<const uint4*>(
                &A[(size_t)(bm * 64 + row) * 8192 + k0 + gg * 8]);
            *reinterpret_cast<uint4*>((char*)As + row * 64 + ((gg ^ ((row >> 1) & 3)) << 4)) = va;
            const uint4 vb = *reinterpret_cast<const uint4*>(
                &Bw[(size_t)(bn * 64 + row) * 8192 + k0 + gg * 8]);
            *reinterpret_cast<uint4*>((char*)Bs + row * 64 + ((gg ^ ((row >> 1) & 3)) << 4)) = vb;
        }
        __syncthreads();
        bf16x8 a[4], b;
        #pragma unroll
        for (int mt = 0; mt < 4; ++mt) {
            const int r = mt * 16 + l15;
            a[mt] = ld_frag(asb + r * 64 + ((g ^ ((r >> 1) & 3)) << 4));
        }
        {
            const int r = wave * 16 + l15;
            b = ld_frag(bsb + r * 64 + ((g ^ ((r >> 1) & 3)) << 4));
        }
        #pragma unroll
        for (int mt = 0; mt < 4; ++mt)
            acc[mt] = __builtin_amdgcn_mfma_f32_16x16x32_bf16(a[mt], b, acc[mt], 0, 0, 0);
    }

    float* Cp = C + (size_t)kz * 512 * 256;
    const int col = bn * 64 + wave * 16 + l15;
    #pragma unroll
    for (int mt = 0; mt < 4; ++mt) {
        #pragma unroll
        for (int r = 0; r < 4; ++r) {
            const int row = bm * 64 + mt * 16 + g * 4 + r;
            Cp[(size_t)row * 256 + col] = acc[mt][r];
        }
    }
}

// ---------------- heads: sum 16 FC partials -> BN+ReLU -> two 256->64 FC+BN+ReLU -> dots ----
__global__ __launch_bounds__(128) void k_heads(
    const float* __restrict__ sraw, const float* __restrict__ fcb,
    const float* __restrict__ fg, const float* __restrict__ fb,
    const float* __restrict__ fm, const float* __restrict__ fv,
    const float* __restrict__ cw1, const float* __restrict__ cb1,
    const float* __restrict__ cg, const float* __restrict__ cbb,
    const float* __restrict__ cm, const float* __restrict__ cv,
    const float* __restrict__ cw2, const float* __restrict__ cb2,
    const float* __restrict__ mw1, const float* __restrict__ mb1,
    const float* __restrict__ mg, const float* __restrict__ mbb,
    const float* __restrict__ mm, const float* __restrict__ mv,
    const float* __restrict__ mw2, const float* __restrict__ mb2,
    float* __restrict__ outp)
{
    __shared__ float sv[256];
    const int b = blockIdx.x, t = threadIdx.x;
    for (int k = t; k < 256; k += 128) {
        float val = fcb[k];
        #pragma unroll
        for (int z = 0; z < 16; ++z) val += sraw[(size_t)z * 131072 + b * 256 + k];
        const float s = fg[k] * rsqrtf(fv[k] + EPS);
        sv[k] = fmaxf(fmaf(val, s, fb[k] - fm[k] * s), 0.f);
    }
    __syncthreads();
    const int j = t & 63;
    const bool isM = (t >= 64);
    const float* w1  = isM ? mw1 : cw1;
    const float* b1  = isM ? mb1 : cb1;
    const float* g1  = isM ? mg  : cg;
    const float* bb1 = isM ? mbb : cbb;
    const float* m1  = isM ? mm  : cm;
    const float* v1  = isM ? mv  : cv;
    const float* w2  = isM ? mw2 : cw2;
    const float* b2  = isM ? mb2 : cb2;
    float d = 0.f;
    const float* wr = w1 + j * 256;
    #pragma unroll 8
    for (int k = 0; k < 256; ++k) d = fmaf(sv[k], wr[k], d);
    d += b1[j];
    const float s1 = g1[j] * rsqrtf(v1[j] + EPS);
    d = fmaxf(fmaf(d, s1, bb1[j] - m1[j] * s1), 0.f);
    float prod = d * w2[j];
    #pragma unroll
    for (int off = 32; off > 0; off >>= 1) prod += __shfl_down(prod, off);
    if (j == 0) outp[(isM ? 512 : 0) + b] = prod + b2[0];
}

extern "C" void kernel_launch(void* const* d_in, const int* in_sizes, int n_in,
                              void* d_out, int out_size, void* d_ws, size_t ws_size,
                              hipStream_t stream)
{
    const float* x    = (const float*)d_in[0];
    const float* w1   = (const float*)d_in[1];
    const float* bn1g = (const float*)d_in[2];
    const float* bn1b = (const float*)d_in[3];
    const float* bn1m = (const float*)d_in[4];
    const float* bn1v = (const float*)d_in[5];
    const float* w2   = (const float*)d_in[6];
    const float* bn2g = (const float*)d_in[7];
    const float* bn2b = (const float*)d_in[8];
    const float* bn2m = (const float*)d_in[9];
    const float* bn2v = (const float*)d_in[10];
    const float* w3   = (const float*)d_in[11];
    const float* bn3g = (const float*)d_in[12];
    const float* bn3b = (const float*)d_in[13];
    const float* bn3m = (const float*)d_in[14];
    const float* bn3v = (const float*)d_in[15];
    const float* fcw  = (const float*)d_in[16];
    const float* fcb  = (const float*)d_in[17];
    const float* bnfg = (const float*)d_in[18];
    const float* bnfb = (const float*)d_in[19];
    const float* bnfm = (const float*)d_in[20];
    const float* bnfv = (const float*)d_in[21];
    const float* cw1  = (const float*)d_in[22];
    const float* cb1  = (const float*)d_in[23];
    const float* bncg = (const float*)d_in[24];
    const float* bncb = (const float*)d_in[25];
    const float* bncm = (const float*)d_in[26];
    const float* bncv = (const float*)d_in[27];
    const float* cw2  = (const float*)d_in[28];
    const float* cb2  = (const float*)d_in[29];
    const float* mw1  = (const float*)d_in[30];
    const float* mb1  = (const float*)d_in[31];
    const float* bnmg = (const float*)d_in[32];
    const float* bnmb = (const float*)d_in[33];
    const float* bnmm = (const float*)d_in[34];
    const float* bnmv = (const float*)d_in[35];
    const float* mw2  = (const float*)d_in[36];
    const float* mb2  = (const float*)d_in[37];

    char* W = (char*)d_ws;
    ushort* h1   = (ushort*)(W);                 // 32 MB
    ushort* h2   = (ushort*)(W + 33554432);      // 16 MB
    ushort* h3   = (ushort*)(W + 50331648);      //  8 MB
    ushort* w1p  = (ushort*)(W + 58720256);      // 10 KB
    ushort* w2p  = (ushort*)(W + 58730496);      // 36 KB
    ushort* w3p  = (ushort*)(W + 58767360);      // 144 KB
    ushort* fcwp = (ushort*)(W + 58914816);      //  4 MB
    float*  sr   = (float*) (W + 63109120);      //  8 MB (16 partials x 512 x 256)
    float* outp = (float*)d_out;

    k_prep<<<128, 256, 0, stream>>>(w1, w2, w3, w1p, w2p, w3p);
    k_prep_fc<<<256, 256, 0, stream>>>(fcw, fcwp);
    k_conv1<<<512 * 8, 256, 0, stream>>>(x, w1p, bn1g, bn1b, bn1m, bn1v, h1);
    k_conv2<<<512 * 4, 256, 0, stream>>>(h1, w2p, bn2g, bn2b, bn2m, bn2v, h2);
    k_conv3<<<512 * 2, 256, 0, stream>>>(h2, w3p, bn3g, bn3b, bn3m, bn3v, h3);
    k_fc<<<dim3(8, 4, 16), 256, 0, stream>>>(h3, fcwp, sr);
    k_heads<<<512, 128, 0, stream>>>(sr, fcb, bnfg, bnfb, bnfm, bnfv,
                                     cw1, cb1, bncg, bncb, bncm, bncv, cw2, cb2,
                                     mw1, mb1, bnmg, bnmb, bnmm, bnmv, mw2, mb2, outp);
}